// Round 1
// baseline (262.664 us; speedup 1.0000x reference)
//
#include <hip/hip_runtime.h>
#include <stdint.h>

typedef short short8 __attribute__((ext_vector_type(8)));
typedef short short4v __attribute__((ext_vector_type(4)));
typedef float f32x4 __attribute__((ext_vector_type(4)));

__device__ __forceinline__ unsigned short bf16_rne(float x){
  unsigned int u = __float_as_uint(x);
  return (unsigned short)((u + 0x7FFFu + ((u >> 16) & 1u)) >> 16);
}
__device__ __forceinline__ float bfval(short s){
  return __uint_as_float(((unsigned int)(unsigned short)s) << 16);
}
__device__ __forceinline__ short8 pack_hi8(float4 a, float4 b){
  short8 r;
  r[0]=(short)bf16_rne(a.x); r[1]=(short)bf16_rne(a.y);
  r[2]=(short)bf16_rne(a.z); r[3]=(short)bf16_rne(a.w);
  r[4]=(short)bf16_rne(b.x); r[5]=(short)bf16_rne(b.y);
  r[6]=(short)bf16_rne(b.z); r[7]=(short)bf16_rne(b.w);
  return r;
}
__device__ __forceinline__ short8 pack_lo8(float4 a, float4 b, short8 h){
  short8 r;
  r[0]=(short)bf16_rne(a.x - bfval(h[0])); r[1]=(short)bf16_rne(a.y - bfval(h[1]));
  r[2]=(short)bf16_rne(a.z - bfval(h[2])); r[3]=(short)bf16_rne(a.w - bfval(h[3]));
  r[4]=(short)bf16_rne(b.x - bfval(h[4])); r[5]=(short)bf16_rne(b.y - bfval(h[5]));
  r[6]=(short)bf16_rne(b.z - bfval(h[6])); r[7]=(short)bf16_rne(b.w - bfval(h[7]));
  return r;
}

// ---------------- generic bt-GEMM with fused fp32->bf16 (hi[,lo]) staging ----
// C[m][n] = sum_k A[m][k]*B[n][k]  (both row-major, contraction over columns)
// NTERMS=3: Markidis split (Ah*Bh + Al*Bh + Ah*Bl). EPI=1: += cvec[row].
template<int NTERMS, int EPI>
__global__ __launch_bounds__(256) void gemm_bt(
    const float* __restrict__ A, const float* __restrict__ B,
    float* __restrict__ C, const float* __restrict__ cvec,
    int N, int K, int lda, int ldb, int ldc,
    long sA, long sB, long sC, long scv)
{
  const int bz = blockIdx.y;
  A += sA * bz; B += sB * bz; C += sC * bz;
  const int tn = N >> 7;
  const int mt = blockIdx.x / tn, nt = blockIdx.x % tn;
  const int m0 = mt << 7, n0 = nt << 7;

  __shared__ short Ah[4096], Bh2[4096], Al[4096], Bl[4096];

  const int t = threadIdx.x;
  const int lane = t & 63, wid = t >> 6;
  const int rowS = t >> 1, kh = t & 1;          // staging: row 0..127, k-half
  const int wr = wid >> 1, wc = wid & 1;        // wave -> 64x64 subtile
  const int fr = lane & 15, fg = lane >> 4;     // frag row, k-group

  const float* Ap = A + (long)(m0 + rowS) * lda + kh * 16;
  const float* Bp = B + (long)(n0 + rowS) * ldb + kh * 16;

  f32x4 acc[4][4];
  const f32x4 Z = {0.f, 0.f, 0.f, 0.f};
  #pragma unroll
  for (int i = 0; i < 4; i++)
    #pragma unroll
    for (int j = 0; j < 4; j++) acc[i][j] = Z;

  const int wbase = rowS * 32;
  const int sw = (rowS >> 1) & 3;
  const int sg0 = kh * 2;

  for (int k0 = 0; k0 < K; k0 += 32){
    __syncthreads();
    {
      const float4* pa = (const float4*)(Ap + k0);
      float4 a0 = pa[0], a1 = pa[1], a2 = pa[2], a3 = pa[3];
      const float4* pb = (const float4*)(Bp + k0);
      float4 b0 = pb[0], b1 = pb[1], b2 = pb[2], b3 = pb[3];
      short8 ha0 = pack_hi8(a0, a1), ha1 = pack_hi8(a2, a3);
      short8 hb0 = pack_hi8(b0, b1), hb1 = pack_hi8(b2, b3);
      *(short8*)&Ah [wbase + (((sg0+0)^sw)<<3)] = ha0;
      *(short8*)&Ah [wbase + (((sg0+1)^sw)<<3)] = ha1;
      *(short8*)&Bh2[wbase + (((sg0+0)^sw)<<3)] = hb0;
      *(short8*)&Bh2[wbase + (((sg0+1)^sw)<<3)] = hb1;
      if (NTERMS == 3){
        short8 la0 = pack_lo8(a0, a1, ha0), la1 = pack_lo8(a2, a3, ha1);
        short8 lb0 = pack_lo8(b0, b1, hb0), lb1 = pack_lo8(b2, b3, hb1);
        *(short8*)&Al[wbase + (((sg0+0)^sw)<<3)] = la0;
        *(short8*)&Al[wbase + (((sg0+1)^sw)<<3)] = la1;
        *(short8*)&Bl[wbase + (((sg0+0)^sw)<<3)] = lb0;
        *(short8*)&Bl[wbase + (((sg0+1)^sw)<<3)] = lb1;
      }
    }
    __syncthreads();
    short8 fa[4], fb[4], fal[4], fbl[4];
    #pragma unroll
    for (int mi = 0; mi < 4; mi++){
      int r = wr * 64 + mi * 16 + fr;
      int idx = r * 32 + ((fg ^ ((r >> 1) & 3)) << 3);
      fa[mi] = *(const short8*)&Ah[idx];
      if (NTERMS == 3) fal[mi] = *(const short8*)&Al[idx];
    }
    #pragma unroll
    for (int ni = 0; ni < 4; ni++){
      int r = wc * 64 + ni * 16 + fr;
      int idx = r * 32 + ((fg ^ ((r >> 1) & 3)) << 3);
      fb[ni] = *(const short8*)&Bh2[idx];
      if (NTERMS == 3) fbl[ni] = *(const short8*)&Bl[idx];
    }
    #pragma unroll
    for (int mi = 0; mi < 4; mi++)
      #pragma unroll
      for (int ni = 0; ni < 4; ni++){
        acc[mi][ni] = __builtin_amdgcn_mfma_f32_16x16x32_bf16(fa[mi], fb[ni], acc[mi][ni], 0, 0, 0);
        if (NTERMS == 3){
          acc[mi][ni] = __builtin_amdgcn_mfma_f32_16x16x32_bf16(fal[mi], fb[ni],  acc[mi][ni], 0, 0, 0);
          acc[mi][ni] = __builtin_amdgcn_mfma_f32_16x16x32_bf16(fa[mi],  fbl[ni], acc[mi][ni], 0, 0, 0);
        }
      }
  }
  #pragma unroll
  for (int mi = 0; mi < 4; mi++)
    #pragma unroll
    for (int ni = 0; ni < 4; ni++){
      int gr0 = m0 + wr * 64 + mi * 16 + fg * 4;
      int gc  = n0 + wc * 64 + ni * 16 + fr;
      #pragma unroll
      for (int j = 0; j < 4; j++){
        float o = acc[mi][ni][j];
        if (EPI == 1) o += cvec[scv * bz + gr0 + j];
        C[(long)(gr0 + j) * ldc + gc] = o;
      }
    }
}

// ---------------- GEMM1: Mt[b][kc][qc] = sum_s k[b][s][kc]*q[b][s][qc] -------
// split-K over 8 s-chunks of 1024; transposed fused-convert staging; also
// accumulates column sums of q (blocks mt==0) and k (blocks nt==0).
__global__ __launch_bounds__(256) void gemm1_tn(
    const float* __restrict__ q, const float* __restrict__ k,
    float* __restrict__ mtp, float* __restrict__ sqp, float* __restrict__ skp)
{
  const int b = blockIdx.z, sp = blockIdx.y;
  const int mt = blockIdx.x >> 2, nt = blockIdx.x & 3;
  const float* qb = q + (long)b * 8192 * 512;
  const float* kb = k + (long)b * 8192 * 512;

  __shared__ short Ah[4096], Al[4096], Bh[4096], Bl[4096];

  const int t = threadIdx.x;
  const int lane = t & 63, wid = t >> 6;
  const int c0 = t & 31;        // col group base (cols c0 + 32*i)
  const int sg = t >> 5;        // s-group 0..7
  const int s0 = sg * 4;
  const int wr = wid >> 1, wc = wid & 1;
  const int fr = lane & 15, fg = lane >> 4;

  float sumq[4] = {0.f,0.f,0.f,0.f}, sumk[4] = {0.f,0.f,0.f,0.f};
  f32x4 acc[4][4];
  const f32x4 Z = {0.f,0.f,0.f,0.f};
  #pragma unroll
  for (int i = 0; i < 4; i++)
    #pragma unroll
    for (int j = 0; j < 4; j++) acc[i][j] = Z;

  const int seg = s0 >> 3, soff = s0 & 7;

  for (int step = 0; step < 32; ++step){
    const long sbase = (long)sp * 1024 + step * 32;
    __syncthreads();
    #pragma unroll
    for (int i = 0; i < 4; i++){
      const int c = c0 + 32 * i;
      float va[4], vb[4];
      #pragma unroll
      for (int r = 0; r < 4; r++){
        va[r] = kb[(sbase + s0 + r) * 512 + mt * 128 + c];
        vb[r] = qb[(sbase + s0 + r) * 512 + nt * 128 + c];
      }
      sumk[i] += va[0] + va[1] + va[2] + va[3];
      sumq[i] += vb[0] + vb[1] + vb[2] + vb[3];
      const int idx = c * 32 + (((seg) ^ ((c >> 1) & 3)) << 3) + soff;
      short4v hA, lA, hB, lB;
      #pragma unroll
      for (int r = 0; r < 4; r++){
        unsigned short h = bf16_rne(va[r]);
        hA[r] = (short)h; lA[r] = (short)bf16_rne(va[r] - bfval((short)h));
        unsigned short g = bf16_rne(vb[r]);
        hB[r] = (short)g; lB[r] = (short)bf16_rne(vb[r] - bfval((short)g));
      }
      *(short4v*)&Ah[idx] = hA; *(short4v*)&Al[idx] = lA;
      *(short4v*)&Bh[idx] = hB; *(short4v*)&Bl[idx] = lB;
    }
    __syncthreads();
    short8 fa[4], fal[4], fb[4], fbl[4];
    #pragma unroll
    for (int mi = 0; mi < 4; mi++){
      int r = wr * 64 + mi * 16 + fr;
      int idx = r * 32 + ((fg ^ ((r >> 1) & 3)) << 3);
      fa[mi]  = *(const short8*)&Ah[idx];
      fal[mi] = *(const short8*)&Al[idx];
    }
    #pragma unroll
    for (int ni = 0; ni < 4; ni++){
      int r = wc * 64 + ni * 16 + fr;
      int idx = r * 32 + ((fg ^ ((r >> 1) & 3)) << 3);
      fb[ni]  = *(const short8*)&Bh[idx];
      fbl[ni] = *(const short8*)&Bl[idx];
    }
    #pragma unroll
    for (int mi = 0; mi < 4; mi++)
      #pragma unroll
      for (int ni = 0; ni < 4; ni++){
        acc[mi][ni] = __builtin_amdgcn_mfma_f32_16x16x32_bf16(fa[mi],  fb[ni],  acc[mi][ni], 0,0,0);
        acc[mi][ni] = __builtin_amdgcn_mfma_f32_16x16x32_bf16(fal[mi], fb[ni],  acc[mi][ni], 0,0,0);
        acc[mi][ni] = __builtin_amdgcn_mfma_f32_16x16x32_bf16(fa[mi],  fbl[ni], acc[mi][ni], 0,0,0);
      }
  }

  float* Cp = mtp + ((long)sp * 4 + b) * (512 * 512);
  #pragma unroll
  for (int mi = 0; mi < 4; mi++)
    #pragma unroll
    for (int ni = 0; ni < 4; ni++){
      int gr0 = mt * 128 + wr * 64 + mi * 16 + fg * 4;
      int gc  = nt * 128 + wc * 64 + ni * 16 + fr;
      #pragma unroll
      for (int j = 0; j < 4; j++)
        Cp[(long)(gr0 + j) * 512 + gc] = acc[mi][ni][j];
    }

  __syncthreads();
  float* red = (float*)Ah;    // 1024 floats
  if (mt == 0){
    #pragma unroll
    for (int i = 0; i < 4; i++) red[sg * 128 + c0 + 32 * i] = sumq[i];
    __syncthreads();
    if (t < 128){
      float s = 0.f;
      #pragma unroll
      for (int g = 0; g < 8; g++) s += red[g * 128 + t];
      sqp[((long)b * 8 + sp) * 512 + nt * 128 + t] = s;
    }
    __syncthreads();
  }
  if (nt == 0){
    #pragma unroll
    for (int i = 0; i < 4; i++) red[sg * 128 + c0 + 32 * i] = sumk[i];
    __syncthreads();
    if (t < 128){
      float s = 0.f;
      #pragma unroll
      for (int g = 0; g < 8; g++) s += red[g * 128 + t];
      skp[((long)b * 8 + sp) * 512 + mt * 128 + t] = s;
    }
  }
}

// ---------------- small kernels ---------------------------------------------
__global__ __launch_bounds__(256) void reduceM(const float* __restrict__ p, float* __restrict__ o){
  const long i = ((long)blockIdx.x * 256 + threadIdx.x) * 4;
  float4 s = {0.f,0.f,0.f,0.f};
  #pragma unroll
  for (int j = 0; j < 8; j++){
    float4 v = *(const float4*)(p + (long)j * 1048576 + i);
    s.x += v.x; s.y += v.y; s.z += v.z; s.w += v.w;
  }
  *(float4*)(o + i) = s;
}

__global__ __launch_bounds__(256) void transpose512(const float* __restrict__ in, float* __restrict__ outp){
  __shared__ float tile[32][33];
  const int bx = blockIdx.x & 15, by = blockIdx.x >> 4;
  const int tx = threadIdx.x & 31, ty = threadIdx.x >> 5;
  #pragma unroll
  for (int r = 0; r < 4; r++)
    tile[ty + 8*r][tx] = in[(long)(by*32 + ty + 8*r) * 512 + bx*32 + tx];
  __syncthreads();
  #pragma unroll
  for (int r = 0; r < 4; r++)
    outp[(long)(bx*32 + ty + 8*r) * 512 + by*32 + tx] = tile[tx][ty + 8*r];
}

__global__ __launch_bounds__(256) void smallprep(
    const float* __restrict__ sqp, const float* __restrict__ skp,
    const float* __restrict__ Wq, const float* __restrict__ Wk,
    float* __restrict__ wqsq, float* __restrict__ wksk)
{
  const int bid = blockIdx.x;
  const int tau = bid >> 4;
  const int b = (bid >> 2) & 3, ab = bid & 3;
  const float* P = tau ? skp : sqp;
  const float* W = tau ? Wk : Wq;
  float* O = tau ? wksk : wqsq;
  __shared__ float sv[512];
  const int t = threadIdx.x;
  for (int i = t; i < 512; i += 256){
    float s = 0.f;
    #pragma unroll
    for (int g = 0; g < 8; g++) s += P[((long)b * 8 + g) * 512 + i];
    sv[i] = s;
  }
  __syncthreads();
  const int a = ab * 128 + (t >> 1), half = t & 1;
  const float* Wr = W + (long)a * 512 + half * 256;
  const float* sp2 = sv + half * 256;
  float d = 0.f;
  #pragma unroll 8
  for (int j = 0; j < 256; j++) d += Wr[j] * sp2[j];
  d += __shfl_xor(d, 1);
  if (!half) O[(long)b * 512 + a] = d;
}

__global__ __launch_bounds__(256) void softmax_k(
    const float* __restrict__ num, float* __restrict__ attn, float* __restrict__ cv,
    const float* __restrict__ wqsq, const float* __restrict__ wksk,
    const float* __restrict__ bq, const float* __restrict__ bk,
    const float* __restrict__ bv, const int* __restrict__ gt)
{
  const int a = blockIdx.x, b = blockIdx.y;
  const int t = threadIdx.x;
  const int lane = t & 63, wid = t >> 6;
  __shared__ unsigned char gf[512];
  __shared__ float red[4];
  gf[t] = 0; gf[t + 256] = 0;
  __syncthreads();
  if (t < 64) gf[gt[t]] = 1;
  __syncthreads();

  const float* row = num + ((long)b * 512 + a) * 512;
  const float bqa = bq[a], wqa = wqsq[b * 512 + a];
  const int ga = gf[a];
  const int c0 = t, c1 = t + 256;
  float l0 = (row[c0] + wqa * bk[c0] + bqa * wksk[b*512 + c0] + 8192.0f * bqa * bk[c0]) * 0.04419417382415922f;
  float l1 = (row[c1] + wqa * bk[c1] + bqa * wksk[b*512 + c1] + 8192.0f * bqa * bk[c1]) * 0.04419417382415922f;
  if (a < c0 && !ga && !gf[c0]) l0 = -1e30f;
  if (a < c1 && !ga && !gf[c1]) l1 = -1e30f;

  float m = fmaxf(l0, l1);
  #pragma unroll
  for (int o = 32; o; o >>= 1) m = fmaxf(m, __shfl_xor(m, o));
  if (lane == 0) red[wid] = m;
  __syncthreads();
  m = fmaxf(fmaxf(red[0], red[1]), fmaxf(red[2], red[3]));
  __syncthreads();

  float e0 = __expf(l0 - m), e1 = __expf(l1 - m);
  float s = e0 + e1;
  #pragma unroll
  for (int o = 32; o; o >>= 1) s += __shfl_xor(s, o);
  if (lane == 0) red[wid] = s;
  __syncthreads();
  s = red[0] + red[1] + red[2] + red[3];
  __syncthreads();
  const float inv = 1.0f / s;
  const float a0 = e0 * inv, a1 = e1 * inv;
  float* arow = attn + ((long)b * 512 + a) * 512;
  arow[c0] = a0; arow[c1] = a1;

  float cp = a0 * bv[c0] + a1 * bv[c1];
  #pragma unroll
  for (int o = 32; o; o >>= 1) cp += __shfl_xor(cp, o);
  if (lane == 0) red[wid] = cp;
  __syncthreads();
  if (t == 0) cv[(long)b * 512 + a] = red[0] + red[1] + red[2] + red[3];
}

// ---------------- launch -----------------------------------------------------
extern "C" void kernel_launch(void* const* d_in, const int* in_sizes, int n_in,
                              void* d_out, int out_size, void* d_ws, size_t ws_size,
                              hipStream_t stream) {
  const float* q  = (const float*)d_in[0];
  const float* k  = (const float*)d_in[1];
  const float* v  = (const float*)d_in[2];
  const float* Wq = (const float*)d_in[3];
  const float* bq = (const float*)d_in[4];
  const float* Wk = (const float*)d_in[5];
  const float* bk = (const float*)d_in[6];
  const float* Wv = (const float*)d_in[7];
  const float* bv = (const float*)d_in[8];
  const int*   gt = (const int*)d_in[9];
  float* out = (float*)d_out;

  float* w = (float*)d_ws;
  float* mtp  = w;                 // 8 * 1,048,576
  float* mt   = mtp  + 8388608;    // 1,048,576  (Mt[b][kc][qc] = M^T)
  float* t1   = mt   + 1048576;    // 1,048,576
  float* numb = t1   + 1048576;    // 1,048,576
  float* attn = numb + 1048576;    // 1,048,576
  float* a2b  = attn + 1048576;    // 1,048,576
  float* wvT  = a2b  + 1048576;    // 262,144
  float* sqp  = wvT  + 262144;     // 16,384
  float* skp  = sqp  + 16384;      // 16,384
  float* wqsq = skp  + 16384;      // 2,048
  float* wksk = wqsq + 2048;       // 2,048
  float* cv   = wksk + 2048;       // 2,048   total ~55.6 MB

  transpose512<<<256, 256, 0, stream>>>(Wv, wvT);
  gemm1_tn<<<dim3(16, 8, 4), 256, 0, stream>>>(q, k, mtp, sqp, skp);
  reduceM<<<1024, 256, 0, stream>>>(mtp, mt);
  smallprep<<<32, 256, 0, stream>>>(sqp, skp, Wq, Wk, wqsq, wksk);
  // T1[a][j] = sum_i Wq[a][i] * Mt[j][i]
  gemm_bt<3,0><<<dim3(16, 4), 256, 0, stream>>>(Wq, mt, t1, nullptr,
      512, 512, 512, 512, 512, 0L, 262144L, 262144L, 0L);
  // num[a][c] = sum_j T1[a][j] * Wk[c][j]
  gemm_bt<3,0><<<dim3(16, 4), 256, 0, stream>>>(t1, Wk, numb, nullptr,
      512, 512, 512, 512, 512, 262144L, 0L, 262144L, 0L);
  softmax_k<<<dim3(512, 4), 256, 0, stream>>>(numb, attn, cv, wqsq, wksk, bq, bk, bv, gt);
  // A2[a][i] = sum_c attn[a][c] * WvT[i][c]
  gemm_bt<1,0><<<dim3(16, 4), 256, 0, stream>>>(attn, wvT, a2b, nullptr,
      512, 512, 512, 512, 512, 262144L, 0L, 262144L, 0L);
  // out[a][s] = sum_i A2[a][i] * v[s][i] + cv[a]
  gemm_bt<1,1><<<dim3(256, 4), 256, 0, stream>>>(a2b, v, out, cv,
      8192, 512, 512, 512, 8192, 262144L, 4194304L, 4194304L, 512L);
}

// Round 2
// 255.000 us; speedup vs baseline: 1.0301x; 1.0301x over previous
//
#include <hip/hip_runtime.h>
#include <stdint.h>

typedef short short8 __attribute__((ext_vector_type(8)));
typedef short short4v __attribute__((ext_vector_type(4)));
typedef float f32x4 __attribute__((ext_vector_type(4)));
typedef unsigned short ushort_t;

__device__ __forceinline__ unsigned short bf16_rne(float x){
  unsigned int u = __float_as_uint(x);
  return (unsigned short)((u + 0x7FFFu + ((u >> 16) & 1u)) >> 16);
}

// packed f32->bf16 RNE: dst.lo = bf16(a), dst.hi = bf16(b)
__device__ __forceinline__ unsigned cvt_pk(float a, float b){
  unsigned r;
  asm("v_cvt_pk_bf16_f32 %0, %1, %2" : "=v"(r) : "v"(a), "v"(b));
  return r;
}

// 4 consecutive values -> hi 2 words (RNE) + lo 2 words (exact remainder, RNE)
__device__ __forceinline__ void split4(float a0, float a1, float a2, float a3,
                                       unsigned &h0, unsigned &h1,
                                       unsigned &l0, unsigned &l1){
  h0 = cvt_pk(a0, a1); h1 = cvt_pk(a2, a3);
  float f0 = __uint_as_float(h0 << 16), f1 = __uint_as_float(h0 & 0xFFFF0000u);
  float f2 = __uint_as_float(h1 << 16), f3 = __uint_as_float(h1 & 0xFFFF0000u);
  l0 = cvt_pk(a0 - f0, a1 - f1); l1 = cvt_pk(a2 - f2, a3 - f3);
}
__device__ __forceinline__ uint4 hi8(float4 x, float4 y){
  uint4 h; h.x = cvt_pk(x.x, x.y); h.y = cvt_pk(x.z, x.w);
  h.z = cvt_pk(y.x, y.y); h.w = cvt_pk(y.z, y.w); return h;
}
__device__ __forceinline__ void split8(float4 x, float4 y, uint4 &h, uint4 &l){
  split4(x.x, x.y, x.z, x.w, h.x, h.y, l.x, l.y);
  split4(y.x, y.y, y.z, y.w, h.z, h.w, l.z, l.w);
}
__device__ __forceinline__ short8 comb(short4v a, short4v b){
  short8 r; r[0]=a[0]; r[1]=a[1]; r[2]=a[2]; r[3]=a[3];
  r[4]=b[0]; r[5]=b[1]; r[6]=b[2]; r[7]=b[3]; return r;
}

// ---------------- generic bt-GEMM ------------------------------------------
// C[m][n] = sum_k A[m][k]*B[n][k], both row-major.
// ABF/BBF: operand is bf16 (1) or f32 with fused convert (0).
// NT=3: Markidis 3-term (requires ABF=BBF=0). OB=1: bf16 output. EPI=1: +cvec.
template<int ABF, int BBF, int NT, int EPI, int OB>
__global__ __launch_bounds__(256, 2) void gemm_bt(
    const void* __restrict__ Av, const void* __restrict__ Bv,
    void* __restrict__ Cv, const float* __restrict__ cvec,
    int N, int K, int lda, int ldb, int ldc,
    long sA, long sB, long sC, long scv)
{
  const int bz = blockIdx.y;
  const int tn = N >> 7;
  const int mt = blockIdx.x / tn, nt = blockIdx.x % tn;
  const int m0 = mt << 7, n0 = nt << 7;

  constexpr int AL = (NT == 3) ? 8192 : 4096;   // lo plane at +4096 when NT=3
  __shared__ __align__(16) short Ah[AL];
  __shared__ __align__(16) short Bh2[AL];

  const int t = threadIdx.x;
  const int lane = t & 63, wid = t >> 6;
  const int rowS = t >> 1, kh = t & 1;
  const int wr = wid >> 1, wc = wid & 1;
  const int fr = lane & 15, fg = lane >> 4;

  f32x4 acc[4][4];
  const f32x4 Z = {0.f, 0.f, 0.f, 0.f};
  #pragma unroll
  for (int i = 0; i < 4; i++)
    #pragma unroll
    for (int j = 0; j < 4; j++) acc[i][j] = Z;

  const int wbase = rowS * 32;
  const int sw = (rowS >> 1) & 3;
  const int i0 = wbase + ((((kh << 1) + 0) ^ sw) << 3);
  const int i1 = wbase + ((((kh << 1) + 1) ^ sw) << 3);

  const float*    Afp = (const float*)Av   + sA * bz + (long)(m0 + rowS) * lda + kh * 16;
  const ushort_t* Abp = (const ushort_t*)Av + sA * bz + (long)(m0 + rowS) * lda + kh * 16;
  const float*    Bfp = (const float*)Bv   + sB * bz + (long)(n0 + rowS) * ldb + kh * 16;
  const ushort_t* Bbp = (const ushort_t*)Bv + sB * bz + (long)(n0 + rowS) * ldb + kh * 16;

  for (int k0 = 0; k0 < K; k0 += 32){
    // issue loads before the barrier so VMEM overlaps the previous compute
    float4 a0, a1, a2, a3, b0, b1, b2, b3;
    short8 as0, as1, bs0, bs1;
    if (ABF == 0){
      const float4* pa = (const float4*)(Afp + k0);
      a0 = pa[0]; a1 = pa[1]; a2 = pa[2]; a3 = pa[3];
    } else {
      const short8* pa = (const short8*)(Abp + k0);
      as0 = pa[0]; as1 = pa[1];
    }
    if (BBF == 0){
      const float4* pb = (const float4*)(Bfp + k0);
      b0 = pb[0]; b1 = pb[1]; b2 = pb[2]; b3 = pb[3];
    } else {
      const short8* pb = (const short8*)(Bbp + k0);
      bs0 = pb[0]; bs1 = pb[1];
    }
    __syncthreads();
    if (ABF == 0){
      if (NT == 3){
        uint4 h0, h1, l0, l1;
        split8(a0, a1, h0, l0); split8(a2, a3, h1, l1);
        *(uint4*)&Ah[i0] = h0; *(uint4*)&Ah[i1] = h1;
        *(uint4*)&Ah[i0 + 4096] = l0; *(uint4*)&Ah[i1 + 4096] = l1;
      } else {
        *(uint4*)&Ah[i0] = hi8(a0, a1); *(uint4*)&Ah[i1] = hi8(a2, a3);
      }
    } else {
      *(short8*)&Ah[i0] = as0; *(short8*)&Ah[i1] = as1;
    }
    if (BBF == 0){
      if (NT == 3){
        uint4 h0, h1, l0, l1;
        split8(b0, b1, h0, l0); split8(b2, b3, h1, l1);
        *(uint4*)&Bh2[i0] = h0; *(uint4*)&Bh2[i1] = h1;
        *(uint4*)&Bh2[i0 + 4096] = l0; *(uint4*)&Bh2[i1 + 4096] = l1;
      } else {
        *(uint4*)&Bh2[i0] = hi8(b0, b1); *(uint4*)&Bh2[i1] = hi8(b2, b3);
      }
    } else {
      *(short8*)&Bh2[i0] = bs0; *(short8*)&Bh2[i1] = bs1;
    }
    __syncthreads();

    short8 fa[4], fb[4], fal[4], fbl[4];
    #pragma unroll
    for (int mi = 0; mi < 4; mi++){
      int r = wr * 64 + mi * 16 + fr;
      int idx = r * 32 + ((fg ^ ((r >> 1) & 3)) << 3);
      fa[mi] = *(const short8*)&Ah[idx];
      if (NT == 3) fal[mi] = *(const short8*)&Ah[idx + 4096];
    }
    #pragma unroll
    for (int ni = 0; ni < 4; ni++){
      int r = wc * 64 + ni * 16 + fr;
      int idx = r * 32 + ((fg ^ ((r >> 1) & 3)) << 3);
      fb[ni] = *(const short8*)&Bh2[idx];
      if (NT == 3) fbl[ni] = *(const short8*)&Bh2[idx + 4096];
    }
    #pragma unroll
    for (int mi = 0; mi < 4; mi++)
      #pragma unroll
      for (int ni = 0; ni < 4; ni++){
        acc[mi][ni] = __builtin_amdgcn_mfma_f32_16x16x32_bf16(fa[mi], fb[ni], acc[mi][ni], 0, 0, 0);
        if (NT == 3){
          acc[mi][ni] = __builtin_amdgcn_mfma_f32_16x16x32_bf16(fal[mi], fb[ni],  acc[mi][ni], 0, 0, 0);
          acc[mi][ni] = __builtin_amdgcn_mfma_f32_16x16x32_bf16(fa[mi],  fbl[ni], acc[mi][ni], 0, 0, 0);
        }
      }
  }

  float*    Cf = (float*)Cv    + sC * bz;
  ushort_t* Cb = (ushort_t*)Cv + sC * bz;
  #pragma unroll
  for (int mi = 0; mi < 4; mi++)
    #pragma unroll
    for (int ni = 0; ni < 4; ni++){
      int gr0 = m0 + wr * 64 + mi * 16 + fg * 4;
      int gc  = n0 + wc * 64 + ni * 16 + fr;
      #pragma unroll
      for (int j = 0; j < 4; j++){
        float o = acc[mi][ni][j];
        if (EPI == 1) o += cvec[scv * bz + gr0 + j];
        if (OB == 1) Cb[(long)(gr0 + j) * ldc + gc] = bf16_rne(o);
        else         Cf[(long)(gr0 + j) * ldc + gc] = o;
      }
    }
}

// ---------------- GEMM1: Mt[b][kc][qc] = sum_s k[b][s][kc]*q[b][s][qc] ------
// float4 loads + in-register 4x4 transpose + cvt_pk + interleaved hi/lo b128
// LDS writes. split-K over 8 s-chunks of 1024. Fused column sums of q,k.
__global__ __launch_bounds__(256, 2) void gemm1_tn(
    const float* __restrict__ q, const float* __restrict__ k,
    float* __restrict__ mtp, float* __restrict__ sqp, float* __restrict__ skp)
{
  const int b = blockIdx.z, sp = blockIdx.y;
  const int mt = blockIdx.x >> 2, nt = blockIdx.x & 3;
  const float* qb = q + (long)b * 8192 * 512;
  const float* kb = k + (long)b * 8192 * 512;

  // per tensor: [c:128][unit:8][ hi 8B | lo 8B ] = 16 KB; unit u = s-rows 4u..4u+3
  __shared__ __align__(16) unsigned char As[16384];
  __shared__ __align__(16) unsigned char Bs[16384];

  const int t = threadIdx.x;
  const int lam = t & 31, sg = t >> 5;
  const int lane = t & 63, wid = t >> 6;
  const int wr = wid >> 1, wc = wid & 1;
  const int fr = lane & 15, fg = lane >> 4;

  f32x4 acc[4][4];
  const f32x4 Z = {0.f, 0.f, 0.f, 0.f};
  #pragma unroll
  for (int i = 0; i < 4; i++)
    #pragma unroll
    for (int j = 0; j < 4; j++) acc[i][j] = Z;

  float sumk4[4] = {0.f, 0.f, 0.f, 0.f};
  float sumq4[4] = {0.f, 0.f, 0.f, 0.f};

  int wA[4];
  #pragma unroll
  for (int j = 0; j < 4; j++){
    int c = lam * 4 + j;
    int swc = ((c >> 2) ^ ((c & 3) << 1)) & 7;
    wA[j] = c * 128 + ((sg ^ swc) << 4);
  }

  const float* kbase = kb + (long)(sp * 1024 + sg * 4) * 512 + mt * 128 + lam * 4;
  const float* qbase = qb + (long)(sp * 1024 + sg * 4) * 512 + nt * 128 + lam * 4;

  for (int step = 0; step < 32; ++step){
    const float* pK = kbase + (long)step * 16384;
    const float* pQ = qbase + (long)step * 16384;
    float4 ka0 = *(const float4*)(pK);
    float4 ka1 = *(const float4*)(pK + 512);
    float4 ka2 = *(const float4*)(pK + 1024);
    float4 ka3 = *(const float4*)(pK + 1536);
    float4 qa0 = *(const float4*)(pQ);
    float4 qa1 = *(const float4*)(pQ + 512);
    float4 qa2 = *(const float4*)(pQ + 1024);
    float4 qa3 = *(const float4*)(pQ + 1536);
    __syncthreads();
    #pragma unroll
    for (int j = 0; j < 4; j++){
      float a0 = ((const float*)&ka0)[j], a1 = ((const float*)&ka1)[j];
      float a2 = ((const float*)&ka2)[j], a3 = ((const float*)&ka3)[j];
      sumk4[j] += (a0 + a1) + (a2 + a3);
      unsigned h0, h1, l0, l1;
      split4(a0, a1, a2, a3, h0, h1, l0, l1);
      uint4 w; w.x = h0; w.y = h1; w.z = l0; w.w = l1;
      *(uint4*)(As + wA[j]) = w;
    }
    #pragma unroll
    for (int j = 0; j < 4; j++){
      float a0 = ((const float*)&qa0)[j], a1 = ((const float*)&qa1)[j];
      float a2 = ((const float*)&qa2)[j], a3 = ((const float*)&qa3)[j];
      sumq4[j] += (a0 + a1) + (a2 + a3);
      unsigned h0, h1, l0, l1;
      split4(a0, a1, a2, a3, h0, h1, l0, l1);
      uint4 w; w.x = h0; w.y = h1; w.z = l0; w.w = l1;
      *(uint4*)(Bs + wA[j]) = w;
    }
    __syncthreads();

    short8 fa[4], fal[4], fb[4], fbl[4];
    #pragma unroll
    for (int mi = 0; mi < 4; mi++){
      int r = wr * 64 + mi * 16 + fr;
      int swc = ((r >> 2) ^ ((r & 3) << 1)) & 7;
      const unsigned char* bp = As + r * 128;
      int u0 = (((fg << 1) + 0) ^ swc) << 4;
      int u1 = (((fg << 1) + 1) ^ swc) << 4;
      fa[mi]  = comb(*(const short4v*)(bp + u0),     *(const short4v*)(bp + u1));
      fal[mi] = comb(*(const short4v*)(bp + u0 + 8), *(const short4v*)(bp + u1 + 8));
    }
    #pragma unroll
    for (int ni = 0; ni < 4; ni++){
      int r = wc * 64 + ni * 16 + fr;
      int swc = ((r >> 2) ^ ((r & 3) << 1)) & 7;
      const unsigned char* bp = Bs + r * 128;
      int u0 = (((fg << 1) + 0) ^ swc) << 4;
      int u1 = (((fg << 1) + 1) ^ swc) << 4;
      fb[ni]  = comb(*(const short4v*)(bp + u0),     *(const short4v*)(bp + u1));
      fbl[ni] = comb(*(const short4v*)(bp + u0 + 8), *(const short4v*)(bp + u1 + 8));
    }
    #pragma unroll
    for (int mi = 0; mi < 4; mi++)
      #pragma unroll
      for (int ni = 0; ni < 4; ni++){
        acc[mi][ni] = __builtin_amdgcn_mfma_f32_16x16x32_bf16(fa[mi],  fb[ni],  acc[mi][ni], 0, 0, 0);
        acc[mi][ni] = __builtin_amdgcn_mfma_f32_16x16x32_bf16(fal[mi], fb[ni],  acc[mi][ni], 0, 0, 0);
        acc[mi][ni] = __builtin_amdgcn_mfma_f32_16x16x32_bf16(fa[mi],  fbl[ni], acc[mi][ni], 0, 0, 0);
      }
  }

  float* Cp = mtp + ((long)sp * 4 + b) * (512 * 512);
  #pragma unroll
  for (int mi = 0; mi < 4; mi++)
    #pragma unroll
    for (int ni = 0; ni < 4; ni++){
      int gr0 = mt * 128 + wr * 64 + mi * 16 + fg * 4;
      int gc  = nt * 128 + wc * 64 + ni * 16 + fr;
      #pragma unroll
      for (int j = 0; j < 4; j++)
        Cp[(long)(gr0 + j) * 512 + gc] = acc[mi][ni][j];
    }

  __syncthreads();
  float* red = (float*)As;    // 1024 floats
  if (mt == 0){
    #pragma unroll
    for (int j = 0; j < 4; j++) red[sg * 128 + lam * 4 + j] = sumq4[j];
    __syncthreads();
    if (t < 128){
      float s = 0.f;
      #pragma unroll
      for (int g = 0; g < 8; g++) s += red[g * 128 + t];
      sqp[((long)b * 8 + sp) * 512 + nt * 128 + t] = s;
    }
    __syncthreads();
  }
  if (nt == 0){
    #pragma unroll
    for (int j = 0; j < 4; j++) red[sg * 128 + lam * 4 + j] = sumk4[j];
    __syncthreads();
    if (t < 128){
      float s = 0.f;
      #pragma unroll
      for (int g = 0; g < 8; g++) s += red[g * 128 + t];
      skp[((long)b * 8 + sp) * 512 + mt * 128 + t] = s;
    }
  }
}

// ---------------- small kernels ---------------------------------------------
__global__ __launch_bounds__(256) void reduceM(const float* __restrict__ p, float* __restrict__ o){
  const long i = ((long)blockIdx.x * 256 + threadIdx.x) * 4;
  float4 s = {0.f, 0.f, 0.f, 0.f};
  #pragma unroll
  for (int j = 0; j < 8; j++){
    float4 v = *(const float4*)(p + (long)j * 1048576 + i);
    s.x += v.x; s.y += v.y; s.z += v.z; s.w += v.w;
  }
  *(float4*)(o + i) = s;
}

__global__ __launch_bounds__(256) void transpose512(const float* __restrict__ in, float* __restrict__ outp){
  __shared__ float tile[32][33];
  const int bx = blockIdx.x & 15, by = blockIdx.x >> 4;
  const int tx = threadIdx.x & 31, ty = threadIdx.x >> 5;
  #pragma unroll
  for (int r = 0; r < 4; r++)
    tile[ty + 8*r][tx] = in[(long)(by*32 + ty + 8*r) * 512 + bx*32 + tx];
  __syncthreads();
  #pragma unroll
  for (int r = 0; r < 4; r++)
    outp[(long)(bx*32 + ty + 8*r) * 512 + by*32 + tx] = tile[tx][ty + 8*r];
}

__global__ __launch_bounds__(256) void smallprep(
    const float* __restrict__ sqp, const float* __restrict__ skp,
    const float* __restrict__ Wq, const float* __restrict__ Wk,
    float* __restrict__ wqsq, float* __restrict__ wksk)
{
  const int bid = blockIdx.x;
  const int tau = bid >> 4;
  const int b = (bid >> 2) & 3, ab = bid & 3;
  const float* P = tau ? skp : sqp;
  const float* W = tau ? Wk : Wq;
  float* O = tau ? wksk : wqsq;
  __shared__ float sv[512];
  const int t = threadIdx.x;
  for (int i = t; i < 512; i += 256){
    float s = 0.f;
    #pragma unroll
    for (int g = 0; g < 8; g++) s += P[((long)b * 8 + g) * 512 + i];
    sv[i] = s;
  }
  __syncthreads();
  const int a = ab * 128 + (t >> 1), half = t & 1;
  const float* Wr = W + (long)a * 512 + half * 256;
  const float* sp2 = sv + half * 256;
  float d = 0.f;
  #pragma unroll 8
  for (int j = 0; j < 256; j++) d += Wr[j] * sp2[j];
  d += __shfl_xor(d, 1);
  if (!half) O[(long)b * 512 + a] = d;
}

__global__ __launch_bounds__(256) void softmax_k(
    const float* __restrict__ num, float* __restrict__ attn, float* __restrict__ cv,
    const float* __restrict__ wqsq, const float* __restrict__ wksk,
    const float* __restrict__ bq, const float* __restrict__ bk,
    const float* __restrict__ bv, const int* __restrict__ gt)
{
  const int a = blockIdx.x, b = blockIdx.y;
  const int t = threadIdx.x;
  const int lane = t & 63, wid = t >> 6;
  __shared__ unsigned char gf[512];
  __shared__ float red[4];
  gf[t] = 0; gf[t + 256] = 0;
  __syncthreads();
  if (t < 64) gf[gt[t]] = 1;
  __syncthreads();

  const float* row = num + ((long)b * 512 + a) * 512;
  const float bqa = bq[a], wqa = wqsq[b * 512 + a];
  const int ga = gf[a];
  const int c0 = t, c1 = t + 256;
  float l0 = (row[c0] + wqa * bk[c0] + bqa * wksk[b*512 + c0] + 8192.0f * bqa * bk[c0]) * 0.04419417382415922f;
  float l1 = (row[c1] + wqa * bk[c1] + bqa * wksk[b*512 + c1] + 8192.0f * bqa * bk[c1]) * 0.04419417382415922f;
  if (a < c0 && !ga && !gf[c0]) l0 = -1e30f;
  if (a < c1 && !ga && !gf[c1]) l1 = -1e30f;

  float m = fmaxf(l0, l1);
  #pragma unroll
  for (int o = 32; o; o >>= 1) m = fmaxf(m, __shfl_xor(m, o));
  if (lane == 0) red[wid] = m;
  __syncthreads();
  m = fmaxf(fmaxf(red[0], red[1]), fmaxf(red[2], red[3]));
  __syncthreads();

  float e0 = __expf(l0 - m), e1 = __expf(l1 - m);
  float s = e0 + e1;
  #pragma unroll
  for (int o = 32; o; o >>= 1) s += __shfl_xor(s, o);
  if (lane == 0) red[wid] = s;
  __syncthreads();
  s = red[0] + red[1] + red[2] + red[3];
  __syncthreads();
  const float inv = 1.0f / s;
  const float a0 = e0 * inv, a1 = e1 * inv;
  float* arow = attn + ((long)b * 512 + a) * 512;
  arow[c0] = a0; arow[c1] = a1;

  float cp = a0 * bv[c0] + a1 * bv[c1];
  #pragma unroll
  for (int o = 32; o; o >>= 1) cp += __shfl_xor(cp, o);
  if (lane == 0) red[wid] = cp;
  __syncthreads();
  if (t == 0) cv[(long)b * 512 + a] = red[0] + red[1] + red[2] + red[3];
}

// ---------------- launch -----------------------------------------------------
extern "C" void kernel_launch(void* const* d_in, const int* in_sizes, int n_in,
                              void* d_out, int out_size, void* d_ws, size_t ws_size,
                              hipStream_t stream) {
  const float* q  = (const float*)d_in[0];
  const float* k  = (const float*)d_in[1];
  const float* v  = (const float*)d_in[2];
  const float* Wq = (const float*)d_in[3];
  const float* bq = (const float*)d_in[4];
  const float* Wk = (const float*)d_in[5];
  const float* bk = (const float*)d_in[6];
  const float* Wv = (const float*)d_in[7];
  const float* bv = (const float*)d_in[8];
  const int*   gt = (const int*)d_in[9];
  float* out = (float*)d_out;

  float* w = (float*)d_ws;
  float* mtp  = w;                 // 8 * 1,048,576
  float* mt   = mtp  + 8388608;    // 1,048,576  (Mt[b][kc][qc] = M^T)
  float* t1   = mt   + 1048576;    // 1,048,576
  float* numb = t1   + 1048576;    // 1,048,576
  float* attn = numb + 1048576;    // 1,048,576
  float* a2b  = attn + 1048576;    // region reused: a2 as bf16 (1M ushorts)
  float* wvT  = a2b  + 1048576;    // 262,144
  float* sqp  = wvT  + 262144;     // 16,384
  float* skp  = sqp  + 16384;      // 16,384
  float* wqsq = skp  + 16384;      // 2,048
  float* wksk = wqsq + 2048;       // 2,048
  float* cv   = wksk + 2048;       // 2,048
  ushort_t* a2h = (ushort_t*)a2b;

  transpose512<<<256, 256, 0, stream>>>(Wv, wvT);
  gemm1_tn<<<dim3(16, 8, 4), 256, 0, stream>>>(q, k, mtp, sqp, skp);
  reduceM<<<1024, 256, 0, stream>>>(mtp, mt);
  smallprep<<<32, 256, 0, stream>>>(sqp, skp, Wq, Wk, wqsq, wksk);
  // T1[a][j] = sum_i Wq[a][i] * Mt[j][i]
  gemm_bt<0,0,3,0,0><<<dim3(16, 4), 256, 0, stream>>>(Wq, mt, t1, nullptr,
      512, 512, 512, 512, 512, 0L, 262144L, 262144L, 0L);
  // num[a][c] = sum_j T1[a][j] * Wk[c][j]
  gemm_bt<0,0,3,0,0><<<dim3(16, 4), 256, 0, stream>>>(t1, Wk, numb, nullptr,
      512, 512, 512, 512, 512, 262144L, 0L, 262144L, 0L);
  softmax_k<<<dim3(512, 4), 256, 0, stream>>>(numb, attn, cv, wqsq, wksk, bq, bk, bv, gt);
  // A2[a][i] = sum_c attn[a][c] * WvT[i][c]  -> bf16 output
  gemm_bt<0,0,1,0,1><<<dim3(16, 4), 256, 0, stream>>>(attn, wvT, a2h, nullptr,
      512, 512, 512, 512, 512, 262144L, 0L, 262144L, 0L);
  // out[a][s] = sum_i A2[a][i] * v[s][i] + cv[a]   (A is bf16)
  gemm_bt<1,0,1,1,0><<<dim3(256, 4), 256, 0, stream>>>(a2h, v, out, cv,
      8192, 512, 512, 512, 8192, 262144L, 4194304L, 4194304L, 512L);
}

// Round 3
// 233.804 us; speedup vs baseline: 1.1234x; 1.0907x over previous
//
#include <hip/hip_runtime.h>
#include <stdint.h>

typedef short short8 __attribute__((ext_vector_type(8)));
typedef short short4v __attribute__((ext_vector_type(4)));
typedef float f32x4 __attribute__((ext_vector_type(4)));
typedef unsigned short ushort_t;

__device__ __forceinline__ unsigned short bf16_rne(float x){
  unsigned int u = __float_as_uint(x);
  return (unsigned short)((u + 0x7FFFu + ((u >> 16) & 1u)) >> 16);
}

// packed f32->bf16 RNE: dst.lo = bf16(a), dst.hi = bf16(b)
__device__ __forceinline__ unsigned cvt_pk(float a, float b){
  unsigned r;
  asm("v_cvt_pk_bf16_f32 %0, %1, %2" : "=v"(r) : "v"(a), "v"(b));
  return r;
}

// 4 consecutive values -> hi 2 words (RNE) + lo 2 words (exact remainder, RNE)
__device__ __forceinline__ void split4(float a0, float a1, float a2, float a3,
                                       unsigned &h0, unsigned &h1,
                                       unsigned &l0, unsigned &l1){
  h0 = cvt_pk(a0, a1); h1 = cvt_pk(a2, a3);
  float f0 = __uint_as_float(h0 << 16), f1 = __uint_as_float(h0 & 0xFFFF0000u);
  float f2 = __uint_as_float(h1 << 16), f3 = __uint_as_float(h1 & 0xFFFF0000u);
  l0 = cvt_pk(a0 - f0, a1 - f1); l1 = cvt_pk(a2 - f2, a3 - f3);
}
__device__ __forceinline__ uint4 hi8(float4 x, float4 y){
  uint4 h; h.x = cvt_pk(x.x, x.y); h.y = cvt_pk(x.z, x.w);
  h.z = cvt_pk(y.x, y.y); h.w = cvt_pk(y.z, y.w); return h;
}
__device__ __forceinline__ void split8(float4 x, float4 y, uint4 &h, uint4 &l){
  split4(x.x, x.y, x.z, x.w, h.x, h.y, l.x, l.y);
  split4(y.x, y.y, y.z, y.w, h.z, h.w, l.z, l.w);
}
__device__ __forceinline__ short8 comb(short4v a, short4v b){
  short8 r; r[0]=a[0]; r[1]=a[1]; r[2]=a[2]; r[3]=a[3];
  r[4]=b[0]; r[5]=b[1]; r[6]=b[2]; r[7]=b[3]; return r;
}

// ---------------- generic bt-GEMM ------------------------------------------
// C[m][n] = sum_k A[m][k]*B[n][k], both row-major.
// ABF/BBF: operand is bf16 (1) or f32 with fused convert (0).
// NT=3: Markidis 3-term (requires ABF=BBF=0). OB=1: bf16 output. EPI=1: +cvec.
// Software-pipelined: loads for step N+1 issued before step N's MFMAs.
template<int ABF, int BBF, int NT, int EPI, int OB>
__global__ __launch_bounds__(256, 2) void gemm_bt(
    const void* __restrict__ Av, const void* __restrict__ Bv,
    void* __restrict__ Cv, const float* __restrict__ cvec,
    int N, int K, int lda, int ldb, int ldc,
    long sA, long sB, long sC, long scv)
{
  const int bz = blockIdx.y;
  const int tn = N >> 7;
  const int mt = blockIdx.x / tn, nt = blockIdx.x % tn;
  const int m0 = mt << 7, n0 = nt << 7;

  constexpr int AL = (NT == 3) ? 8192 : 4096;   // lo plane at +4096 when NT=3
  __shared__ __align__(16) short Ah[AL];
  __shared__ __align__(16) short Bh2[AL];

  const int t = threadIdx.x;
  const int lane = t & 63, wid = t >> 6;
  const int rowS = t >> 1, kh = t & 1;
  const int wr = wid >> 1, wc = wid & 1;
  const int fr = lane & 15, fg = lane >> 4;

  f32x4 acc[4][4];
  const f32x4 Z = {0.f, 0.f, 0.f, 0.f};
  #pragma unroll
  for (int i = 0; i < 4; i++)
    #pragma unroll
    for (int j = 0; j < 4; j++) acc[i][j] = Z;

  const int wbase = rowS * 32;
  const int sw = (rowS >> 1) & 3;
  const int i0 = wbase + ((((kh << 1) + 0) ^ sw) << 3);
  const int i1 = wbase + ((((kh << 1) + 1) ^ sw) << 3);

  const float*    Afp = (const float*)Av   + sA * bz + (long)(m0 + rowS) * lda + kh * 16;
  const ushort_t* Abp = (const ushort_t*)Av + sA * bz + (long)(m0 + rowS) * lda + kh * 16;
  const float*    Bfp = (const float*)Bv   + sB * bz + (long)(n0 + rowS) * ldb + kh * 16;
  const ushort_t* Bbp = (const ushort_t*)Bv + sB * bz + (long)(n0 + rowS) * ldb + kh * 16;

  // preload step 0
  float4 a0, a1, a2, a3, b0, b1, b2, b3;
  short8 as0, as1, bs0, bs1;
  if (ABF == 0){
    const float4* pa = (const float4*)(Afp);
    a0 = pa[0]; a1 = pa[1]; a2 = pa[2]; a3 = pa[3];
  } else {
    const short8* pa = (const short8*)(Abp);
    as0 = pa[0]; as1 = pa[1];
  }
  if (BBF == 0){
    const float4* pb = (const float4*)(Bfp);
    b0 = pb[0]; b1 = pb[1]; b2 = pb[2]; b3 = pb[3];
  } else {
    const short8* pb = (const short8*)(Bbp);
    bs0 = pb[0]; bs1 = pb[1];
  }

  for (int k0 = 0; k0 < K; k0 += 32){
    __syncthreads();
    if (ABF == 0){
      if (NT == 3){
        uint4 h0, h1, l0, l1;
        split8(a0, a1, h0, l0); split8(a2, a3, h1, l1);
        *(uint4*)&Ah[i0] = h0; *(uint4*)&Ah[i1] = h1;
        *(uint4*)&Ah[i0 + 4096] = l0; *(uint4*)&Ah[i1 + 4096] = l1;
      } else {
        *(uint4*)&Ah[i0] = hi8(a0, a1); *(uint4*)&Ah[i1] = hi8(a2, a3);
      }
    } else {
      *(short8*)&Ah[i0] = as0; *(short8*)&Ah[i1] = as1;
    }
    if (BBF == 0){
      if (NT == 3){
        uint4 h0, h1, l0, l1;
        split8(b0, b1, h0, l0); split8(b2, b3, h1, l1);
        *(uint4*)&Bh2[i0] = h0; *(uint4*)&Bh2[i1] = h1;
        *(uint4*)&Bh2[i0 + 4096] = l0; *(uint4*)&Bh2[i1 + 4096] = l1;
      } else {
        *(uint4*)&Bh2[i0] = hi8(b0, b1); *(uint4*)&Bh2[i1] = hi8(b2, b3);
      }
    } else {
      *(short8*)&Bh2[i0] = bs0; *(short8*)&Bh2[i1] = bs1;
    }
    __syncthreads();

    // prefetch next K-step (redundant reload of last step, branchless-ish)
    {
      const int kn = (k0 + 32 < K) ? (k0 + 32) : k0;
      if (ABF == 0){
        const float4* pa = (const float4*)(Afp + kn);
        a0 = pa[0]; a1 = pa[1]; a2 = pa[2]; a3 = pa[3];
      } else {
        const short8* pa = (const short8*)(Abp + kn);
        as0 = pa[0]; as1 = pa[1];
      }
      if (BBF == 0){
        const float4* pb = (const float4*)(Bfp + kn);
        b0 = pb[0]; b1 = pb[1]; b2 = pb[2]; b3 = pb[3];
      } else {
        const short8* pb = (const short8*)(Bbp + kn);
        bs0 = pb[0]; bs1 = pb[1];
      }
    }

    short8 fa[4], fb[4], fal[4], fbl[4];
    #pragma unroll
    for (int mi = 0; mi < 4; mi++){
      int r = wr * 64 + mi * 16 + fr;
      int idx = r * 32 + ((fg ^ ((r >> 1) & 3)) << 3);
      fa[mi] = *(const short8*)&Ah[idx];
      if (NT == 3) fal[mi] = *(const short8*)&Ah[idx + 4096];
    }
    #pragma unroll
    for (int ni = 0; ni < 4; ni++){
      int r = wc * 64 + ni * 16 + fr;
      int idx = r * 32 + ((fg ^ ((r >> 1) & 3)) << 3);
      fb[ni] = *(const short8*)&Bh2[idx];
      if (NT == 3) fbl[ni] = *(const short8*)&Bh2[idx + 4096];
    }
    #pragma unroll
    for (int mi = 0; mi < 4; mi++)
      #pragma unroll
      for (int ni = 0; ni < 4; ni++){
        acc[mi][ni] = __builtin_amdgcn_mfma_f32_16x16x32_bf16(fa[mi], fb[ni], acc[mi][ni], 0, 0, 0);
        if (NT == 3){
          acc[mi][ni] = __builtin_amdgcn_mfma_f32_16x16x32_bf16(fal[mi], fb[ni],  acc[mi][ni], 0, 0, 0);
          acc[mi][ni] = __builtin_amdgcn_mfma_f32_16x16x32_bf16(fa[mi],  fbl[ni], acc[mi][ni], 0, 0, 0);
        }
      }
  }

  float*    Cf = (float*)Cv    + sC * bz;
  ushort_t* Cb = (ushort_t*)Cv + sC * bz;
  #pragma unroll
  for (int mi = 0; mi < 4; mi++)
    #pragma unroll
    for (int ni = 0; ni < 4; ni++){
      int gr0 = m0 + wr * 64 + mi * 16 + fg * 4;
      int gc  = n0 + wc * 64 + ni * 16 + fr;
      #pragma unroll
      for (int j = 0; j < 4; j++){
        float o = acc[mi][ni][j];
        if (EPI == 1) o += cvec[scv * bz + gr0 + j];
        if (OB == 1) Cb[(long)(gr0 + j) * ldc + gc] = bf16_rne(o);
        else         Cf[(long)(gr0 + j) * ldc + gc] = o;
      }
    }
}

// ---------------- GEMM1: Mt[b][kc][qc] = sum_s k[b][s][kc]*q[b][s][qc] ------
// float4 loads + in-register 4x4 transpose + cvt_pk + interleaved hi/lo b128
// LDS writes. split-K over 8 s-chunks of 1024. Fused column sums of q,k.
// Software-pipelined: loads for step N+1 issued before step N's MFMAs.
__global__ __launch_bounds__(256, 2) void gemm1_tn(
    const float* __restrict__ q, const float* __restrict__ k,
    float* __restrict__ mtp, float* __restrict__ sqp, float* __restrict__ skp)
{
  const int b = blockIdx.z, sp = blockIdx.y;
  const int mt = blockIdx.x >> 2, nt = blockIdx.x & 3;
  const float* qb = q + (long)b * 8192 * 512;
  const float* kb = k + (long)b * 8192 * 512;

  // per tensor: [c:128][unit:8][ hi 8B | lo 8B ] = 16 KB; unit u = s-rows 4u..4u+3
  __shared__ __align__(16) unsigned char As[16384];
  __shared__ __align__(16) unsigned char Bs[16384];

  const int t = threadIdx.x;
  const int lam = t & 31, sg = t >> 5;
  const int lane = t & 63, wid = t >> 6;
  const int wr = wid >> 1, wc = wid & 1;
  const int fr = lane & 15, fg = lane >> 4;

  f32x4 acc[4][4];
  const f32x4 Z = {0.f, 0.f, 0.f, 0.f};
  #pragma unroll
  for (int i = 0; i < 4; i++)
    #pragma unroll
    for (int j = 0; j < 4; j++) acc[i][j] = Z;

  float sumk4[4] = {0.f, 0.f, 0.f, 0.f};
  float sumq4[4] = {0.f, 0.f, 0.f, 0.f};

  int wA[4];
  #pragma unroll
  for (int j = 0; j < 4; j++){
    int c = lam * 4 + j;
    int swc = ((c >> 2) ^ ((c & 3) << 1)) & 7;
    wA[j] = c * 128 + ((sg ^ swc) << 4);
  }

  const float* kbase = kb + (long)(sp * 1024 + sg * 4) * 512 + mt * 128 + lam * 4;
  const float* qbase = qb + (long)(sp * 1024 + sg * 4) * 512 + nt * 128 + lam * 4;

  // preload step 0
  float4 ka0 = *(const float4*)(kbase);
  float4 ka1 = *(const float4*)(kbase + 512);
  float4 ka2 = *(const float4*)(kbase + 1024);
  float4 ka3 = *(const float4*)(kbase + 1536);
  float4 qa0 = *(const float4*)(qbase);
  float4 qa1 = *(const float4*)(qbase + 512);
  float4 qa2 = *(const float4*)(qbase + 1024);
  float4 qa3 = *(const float4*)(qbase + 1536);

  for (int step = 0; step < 32; ++step){
    __syncthreads();
    #pragma unroll
    for (int j = 0; j < 4; j++){
      float a0 = ((const float*)&ka0)[j], a1 = ((const float*)&ka1)[j];
      float a2 = ((const float*)&ka2)[j], a3 = ((const float*)&ka3)[j];
      sumk4[j] += (a0 + a1) + (a2 + a3);
      unsigned h0, h1, l0, l1;
      split4(a0, a1, a2, a3, h0, h1, l0, l1);
      uint4 w; w.x = h0; w.y = h1; w.z = l0; w.w = l1;
      *(uint4*)(As + wA[j]) = w;
    }
    #pragma unroll
    for (int j = 0; j < 4; j++){
      float a0 = ((const float*)&qa0)[j], a1 = ((const float*)&qa1)[j];
      float a2 = ((const float*)&qa2)[j], a3 = ((const float*)&qa3)[j];
      sumq4[j] += (a0 + a1) + (a2 + a3);
      unsigned h0, h1, l0, l1;
      split4(a0, a1, a2, a3, h0, h1, l0, l1);
      uint4 w; w.x = h0; w.y = h1; w.z = l0; w.w = l1;
      *(uint4*)(Bs + wA[j]) = w;
    }
    __syncthreads();

    // prefetch next step (redundant reload of step 31 at the end)
    {
      const int nstep = (step < 31) ? (step + 1) : step;
      const float* pK = kbase + (long)nstep * 16384;
      const float* pQ = qbase + (long)nstep * 16384;
      ka0 = *(const float4*)(pK);
      ka1 = *(const float4*)(pK + 512);
      ka2 = *(const float4*)(pK + 1024);
      ka3 = *(const float4*)(pK + 1536);
      qa0 = *(const float4*)(pQ);
      qa1 = *(const float4*)(pQ + 512);
      qa2 = *(const float4*)(pQ + 1024);
      qa3 = *(const float4*)(pQ + 1536);
    }

    short8 fa[4], fal[4], fb[4], fbl[4];
    #pragma unroll
    for (int mi = 0; mi < 4; mi++){
      int r = wr * 64 + mi * 16 + fr;
      int swc = ((r >> 2) ^ ((r & 3) << 1)) & 7;
      const unsigned char* bp = As + r * 128;
      int u0 = (((fg << 1) + 0) ^ swc) << 4;
      int u1 = (((fg << 1) + 1) ^ swc) << 4;
      fa[mi]  = comb(*(const short4v*)(bp + u0),     *(const short4v*)(bp + u1));
      fal[mi] = comb(*(const short4v*)(bp + u0 + 8), *(const short4v*)(bp + u1 + 8));
    }
    #pragma unroll
    for (int ni = 0; ni < 4; ni++){
      int r = wc * 64 + ni * 16 + fr;
      int swc = ((r >> 2) ^ ((r & 3) << 1)) & 7;
      const unsigned char* bp = Bs + r * 128;
      int u0 = (((fg << 1) + 0) ^ swc) << 4;
      int u1 = (((fg << 1) + 1) ^ swc) << 4;
      fb[ni]  = comb(*(const short4v*)(bp + u0),     *(const short4v*)(bp + u1));
      fbl[ni] = comb(*(const short4v*)(bp + u0 + 8), *(const short4v*)(bp + u1 + 8));
    }
    #pragma unroll
    for (int mi = 0; mi < 4; mi++)
      #pragma unroll
      for (int ni = 0; ni < 4; ni++){
        acc[mi][ni] = __builtin_amdgcn_mfma_f32_16x16x32_bf16(fa[mi],  fb[ni],  acc[mi][ni], 0, 0, 0);
        acc[mi][ni] = __builtin_amdgcn_mfma_f32_16x16x32_bf16(fal[mi], fb[ni],  acc[mi][ni], 0, 0, 0);
        acc[mi][ni] = __builtin_amdgcn_mfma_f32_16x16x32_bf16(fa[mi],  fbl[ni], acc[mi][ni], 0, 0, 0);
      }
  }

  float* Cp = mtp + ((long)sp * 4 + b) * (512 * 512);
  #pragma unroll
  for (int mi = 0; mi < 4; mi++)
    #pragma unroll
    for (int ni = 0; ni < 4; ni++){
      int gr0 = mt * 128 + wr * 64 + mi * 16 + fg * 4;
      int gc  = nt * 128 + wc * 64 + ni * 16 + fr;
      #pragma unroll
      for (int j = 0; j < 4; j++)
        Cp[(long)(gr0 + j) * 512 + gc] = acc[mi][ni][j];
    }

  __syncthreads();
  float* red = (float*)As;    // 1024 floats
  if (mt == 0){
    #pragma unroll
    for (int j = 0; j < 4; j++) red[sg * 128 + lam * 4 + j] = sumq4[j];
    __syncthreads();
    if (t < 128){
      float s = 0.f;
      #pragma unroll
      for (int g = 0; g < 8; g++) s += red[g * 128 + t];
      sqp[((long)b * 8 + sp) * 512 + nt * 128 + t] = s;
    }
    __syncthreads();
  }
  if (nt == 0){
    #pragma unroll
    for (int j = 0; j < 4; j++) red[sg * 128 + lam * 4 + j] = sumk4[j];
    __syncthreads();
    if (t < 128){
      float s = 0.f;
      #pragma unroll
      for (int g = 0; g < 8; g++) s += red[g * 128 + t];
      skp[((long)b * 8 + sp) * 512 + mt * 128 + t] = s;
    }
  }
}

// ---------------- small kernels ---------------------------------------------
__global__ __launch_bounds__(256) void reduceM(const float* __restrict__ p, float* __restrict__ o){
  const long i = ((long)blockIdx.x * 256 + threadIdx.x) * 4;
  float4 s = {0.f, 0.f, 0.f, 0.f};
  #pragma unroll
  for (int j = 0; j < 8; j++){
    float4 v = *(const float4*)(p + (long)j * 1048576 + i);
    s.x += v.x; s.y += v.y; s.z += v.z; s.w += v.w;
  }
  *(float4*)(o + i) = s;
}

__global__ __launch_bounds__(256) void transpose512(const float* __restrict__ in, float* __restrict__ outp){
  __shared__ float tile[32][33];
  const int bx = blockIdx.x & 15, by = blockIdx.x >> 4;
  const int tx = threadIdx.x & 31, ty = threadIdx.x >> 5;
  #pragma unroll
  for (int r = 0; r < 4; r++)
    tile[ty + 8*r][tx] = in[(long)(by*32 + ty + 8*r) * 512 + bx*32 + tx];
  __syncthreads();
  #pragma unroll
  for (int r = 0; r < 4; r++)
    outp[(long)(bx*32 + ty + 8*r) * 512 + by*32 + tx] = tile[tx][ty + 8*r];
}

__global__ __launch_bounds__(256) void smallprep(
    const float* __restrict__ sqp, const float* __restrict__ skp,
    const float* __restrict__ Wq, const float* __restrict__ Wk,
    float* __restrict__ wqsq, float* __restrict__ wksk)
{
  const int bid = blockIdx.x;
  const int tau = bid >> 4;
  const int b = (bid >> 2) & 3, ab = bid & 3;
  const float* P = tau ? skp : sqp;
  const float* W = tau ? Wk : Wq;
  float* O = tau ? wksk : wqsq;
  __shared__ float sv[512];
  const int t = threadIdx.x;
  for (int i = t; i < 512; i += 256){
    float s = 0.f;
    #pragma unroll
    for (int g = 0; g < 8; g++) s += P[((long)b * 8 + g) * 512 + i];
    sv[i] = s;
  }
  __syncthreads();
  const int a = ab * 128 + (t >> 1), half = t & 1;
  const float* Wr = W + (long)a * 512 + half * 256;
  const float* sp2 = sv + half * 256;
  float d = 0.f;
  #pragma unroll 8
  for (int j = 0; j < 256; j++) d += Wr[j] * sp2[j];
  d += __shfl_xor(d, 1);
  if (!half) O[(long)b * 512 + a] = d;
}

__global__ __launch_bounds__(256) void softmax_k(
    const float* __restrict__ num, float* __restrict__ attn, float* __restrict__ cv,
    const float* __restrict__ wqsq, const float* __restrict__ wksk,
    const float* __restrict__ bq, const float* __restrict__ bk,
    const float* __restrict__ bv, const int* __restrict__ gt)
{
  const int a = blockIdx.x, b = blockIdx.y;
  const int t = threadIdx.x;
  const int lane = t & 63, wid = t >> 6;
  __shared__ unsigned char gf[512];
  __shared__ float red[4];
  gf[t] = 0; gf[t + 256] = 0;
  __syncthreads();
  if (t < 64) gf[gt[t]] = 1;
  __syncthreads();

  const float* row = num + ((long)b * 512 + a) * 512;
  const float bqa = bq[a], wqa = wqsq[b * 512 + a];
  const int ga = gf[a];
  const int c0 = t, c1 = t + 256;
  float l0 = (row[c0] + wqa * bk[c0] + bqa * wksk[b*512 + c0] + 8192.0f * bqa * bk[c0]) * 0.04419417382415922f;
  float l1 = (row[c1] + wqa * bk[c1] + bqa * wksk[b*512 + c1] + 8192.0f * bqa * bk[c1]) * 0.04419417382415922f;
  if (a < c0 && !ga && !gf[c0]) l0 = -1e30f;
  if (a < c1 && !ga && !gf[c1]) l1 = -1e30f;

  float m = fmaxf(l0, l1);
  #pragma unroll
  for (int o = 32; o; o >>= 1) m = fmaxf(m, __shfl_xor(m, o));
  if (lane == 0) red[wid] = m;
  __syncthreads();
  m = fmaxf(fmaxf(red[0], red[1]), fmaxf(red[2], red[3]));
  __syncthreads();

  float e0 = __expf(l0 - m), e1 = __expf(l1 - m);
  float s = e0 + e1;
  #pragma unroll
  for (int o = 32; o; o >>= 1) s += __shfl_xor(s, o);
  if (lane == 0) red[wid] = s;
  __syncthreads();
  s = red[0] + red[1] + red[2] + red[3];
  __syncthreads();
  const float inv = 1.0f / s;
  const float a0 = e0 * inv, a1 = e1 * inv;
  float* arow = attn + ((long)b * 512 + a) * 512;
  arow[c0] = a0; arow[c1] = a1;

  float cp = a0 * bv[c0] + a1 * bv[c1];
  #pragma unroll
  for (int o = 32; o; o >>= 1) cp += __shfl_xor(cp, o);
  if (lane == 0) red[wid] = cp;
  __syncthreads();
  if (t == 0) cv[(long)b * 512 + a] = red[0] + red[1] + red[2] + red[3];
}

// ---------------- launch -----------------------------------------------------
extern "C" void kernel_launch(void* const* d_in, const int* in_sizes, int n_in,
                              void* d_out, int out_size, void* d_ws, size_t ws_size,
                              hipStream_t stream) {
  const float* q  = (const float*)d_in[0];
  const float* k  = (const float*)d_in[1];
  const float* v  = (const float*)d_in[2];
  const float* Wq = (const float*)d_in[3];
  const float* bq = (const float*)d_in[4];
  const float* Wk = (const float*)d_in[5];
  const float* bk = (const float*)d_in[6];
  const float* Wv = (const float*)d_in[7];
  const float* bv = (const float*)d_in[8];
  const int*   gt = (const int*)d_in[9];
  float* out = (float*)d_out;

  float* w = (float*)d_ws;
  float* mtp  = w;                 // 8 * 1,048,576
  float* mt   = mtp  + 8388608;    // 1,048,576  (Mt[b][kc][qc] = M^T)
  float* t1   = mt   + 1048576;    // 1,048,576
  float* numb = t1   + 1048576;    // 1,048,576
  float* attn = numb + 1048576;    // 1,048,576
  float* a2b  = attn + 1048576;    // region reused: a2 as bf16 (1M ushorts)
  float* wvT  = a2b  + 1048576;    // 262,144
  float* sqp  = wvT  + 262144;     // 16,384
  float* skp  = sqp  + 16384;      // 16,384
  float* wqsq = skp  + 16384;      // 2,048
  float* wksk = wqsq + 2048;       // 2,048
  float* cv   = wksk + 2048;       // 2,048
  ushort_t* a2h = (ushort_t*)a2b;

  transpose512<<<256, 256, 0, stream>>>(Wv, wvT);
  gemm1_tn<<<dim3(16, 8, 4), 256, 0, stream>>>(q, k, mtp, sqp, skp);
  reduceM<<<1024, 256, 0, stream>>>(mtp, mt);
  smallprep<<<32, 256, 0, stream>>>(sqp, skp, Wq, Wk, wqsq, wksk);
  // T1[a][j] = sum_i Wq[a][i] * Mt[j][i]
  gemm_bt<0,0,3,0,0><<<dim3(16, 4), 256, 0, stream>>>(Wq, mt, t1, nullptr,
      512, 512, 512, 512, 512, 0L, 262144L, 262144L, 0L);
  // num[a][c] = sum_j T1[a][j] * Wk[c][j]
  gemm_bt<0,0,3,0,0><<<dim3(16, 4), 256, 0, stream>>>(t1, Wk, numb, nullptr,
      512, 512, 512, 512, 512, 262144L, 0L, 262144L, 0L);
  softmax_k<<<dim3(512, 4), 256, 0, stream>>>(numb, attn, cv, wqsq, wksk, bq, bk, bv, gt);
  // A2[a][i] = sum_c attn[a][c] * WvT[i][c]  -> bf16 output
  gemm_bt<0,0,1,0,1><<<dim3(16, 4), 256, 0, stream>>>(attn, wvT, a2h, nullptr,
      512, 512, 512, 512, 512, 262144L, 0L, 262144L, 0L);
  // out[a][s] = sum_i A2[a][i] * v[s][i] + cv[a]   (A is bf16)
  gemm_bt<1,0,1,1,0><<<dim3(256, 4), 256, 0, stream>>>(a2h, v, out, cv,
      8192, 512, 512, 512, 8192, 262144L, 4194304L, 4194304L, 512L);
}